// Round 3
// baseline (64.694 us; speedup 1.0000x reference)
//
#include <hip/hip_runtime.h>
#include <stdint.h>

#define NROWS 8192
#define FDIM  256   // K (feature dim)
#define DDIM  64    // N (out dim)

typedef __attribute__((ext_vector_type(8))) short short8;   // 8 bf16 = 4 VGPR (MFMA A/B frag)
typedef __attribute__((ext_vector_type(4))) float floatx4;  // MFMA C/D frag

// Pack two fp32 -> bf16x2, round-to-nearest-even (inputs finite; no NaN path needed).
__device__ inline unsigned int pack2_bf16(float a, float b) {
    unsigned int ua = __float_as_uint(a);
    unsigned int ub = __float_as_uint(b);
    ua += 0x7fffu + ((ua >> 16) & 1u);
    ub += 0x7fffu + ((ub >> 16) & 1u);
    return (ua >> 16) | (ub & 0xffff0000u);
}

// ---------------------------------------------------------------------------
// Fused single-kernel v3. Rationale: R1->R2 proved exec time is not the
// residual; the ~16 us above the 42 us poison-fill floor is dispatch/gap
// overhead. One kernel instead of prep+main removes a launch + gap.
//
// Grid 512 x 256 thr (2 blocks/CU via __launch_bounds__(256,2), 8 waves/CU).
// Block = 16 rows. Phases:
//   1) issue x loads (only HBM-cold read) -> 4 dwordx4/lane in flight
//   2) stage all 2048 W frags into LDS (8 frags/thread; W is L2/L3-hot after
//      the first blocks: 64 KB re-read x512 blocks = 32 MB vs ~34 TB/s L2)
//   3) per-block bias colsum partials (16 coalesced float4 loads/thread)
//   4) barrier; MFMA: waves split K 4-way, 2 ks x 4 nt = 8 MFMAs/wave,
//      B-frags via conflict-free ds_read_b128 (16B/lane contiguous)
//   5) barrier; K-merge via LDS (red aliases the dead frag buffer), wave 0
//      folds exact fp32 bias colsum + 1/256 scale, 16 dword stores.
// LDS: 32 KB frags (aliased by 12 KB red) + 4 KB bias = 36 KB -> 2 blocks/CU.
// Layouts (verified in prior rounds):
//   frag f = ks*256 + nt*64 + lane holds W[ks*32+(lane>>4)*8+j][nt*16+(lane&15)]
//   A[m=lane&15][k=(lane>>4)*8+j]; D col=lane&15, row=(lane>>4)*4+reg
// ---------------------------------------------------------------------------
__global__ __launch_bounds__(256, 2)
void nanembed_fused(const float* __restrict__ x,
                    const float* __restrict__ W,
                    const float* __restrict__ b,
                    float* __restrict__ out)
{
    __shared__ __align__(16) unsigned int frag_lds[2048 * 4];  // 32 KB (later: red)
    __shared__ float4 bias_part[16][16];                       // 4 KB

    const int tid  = threadIdx.x;    // 0..255
    const int lane = tid & 63;
    const int wk   = tid >> 6;       // K-quarter 0..3
    const int q    = lane >> 4;      // quad 0..3
    const int n    = lane & 15;
    const int r0   = blockIdx.x * 16;

    // ---- 1) x loads first: row r0+n, cols wk*64 + ks*32 + q*8 + [0,8).
    const float4* xp = reinterpret_cast<const float4*>(x)
                       + (size_t)(r0 + n) * 64 + wk * 16 + q * 2;
    float4 xv[4];
    #pragma unroll
    for (int ks = 0; ks < 2; ++ks) {
        xv[2 * ks]     = xp[ks * 8];
        xv[2 * ks + 1] = xp[ks * 8 + 1];
    }

    // ---- 2) Stage all 2048 W frags, 8 per thread (L2-hot strided loads,
    //         64B-coalesced per 16-lane group; 4 pack2 + 1 ds_write_b128 each).
    #pragma unroll
    for (int i = 0; i < 8; ++i) {
        const int f  = tid + i * 256;          // 0..2047
        const int ks = f >> 8;
        const int fl = f & 63;
        const int c  = ((f >> 6) & 3) * 16 + (fl & 15);
        const float* wp = W + (size_t)(ks * 32 + (fl >> 4) * 8) * DDIM + c;
        union { short8 s; unsigned int u[4]; } fr;
        fr.u[0] = pack2_bf16(wp[0 * DDIM], wp[1 * DDIM]);
        fr.u[1] = pack2_bf16(wp[2 * DDIM], wp[3 * DDIM]);
        fr.u[2] = pack2_bf16(wp[4 * DDIM], wp[5 * DDIM]);
        fr.u[3] = pack2_bf16(wp[6 * DDIM], wp[7 * DDIM]);
        reinterpret_cast<short8*>(frag_lds)[f] = fr.s;
    }

    // ---- 3) Bias partial colsums: thread (h=tid>>4, c4=tid&15) sums 16 f-rows
    //         of float4 column group c4 (fully coalesced).
    {
        const int c4 = tid & 15;
        const int h  = tid >> 4;               // 0..15
        const float4* bp = reinterpret_cast<const float4*>(b) + c4;
        float4 s = make_float4(0.f, 0.f, 0.f, 0.f);
        #pragma unroll
        for (int f = h * 16; f < h * 16 + 16; ++f) {
            float4 v = bp[(size_t)f * 16];
            s.x += v.x; s.y += v.y; s.z += v.z; s.w += v.w;
        }
        bias_part[h][c4] = s;
    }

    __syncthreads();

    // ---- 4) MFMA: wave wk handles k in [wk*64, +64) -> 2 ks x 4 nt.
    floatx4 acc[4] = {{0.f, 0.f, 0.f, 0.f}, {0.f, 0.f, 0.f, 0.f},
                      {0.f, 0.f, 0.f, 0.f}, {0.f, 0.f, 0.f, 0.f}};
    #pragma unroll
    for (int ks = 0; ks < 2; ++ks) {
        union { short8 s; unsigned int u[4]; } fa;
        float4 v0 = xv[2 * ks], v1 = xv[2 * ks + 1];
        fa.u[0] = pack2_bf16(v0.x, v0.y);
        fa.u[1] = pack2_bf16(v0.z, v0.w);
        fa.u[2] = pack2_bf16(v1.x, v1.y);
        fa.u[3] = pack2_bf16(v1.z, v1.w);
        #pragma unroll
        for (int nt = 0; nt < 4; ++nt) {
            short8 fb = reinterpret_cast<const short8*>(frag_lds)
                            [(wk * 2 + ks) * 256 + nt * 64 + lane];
            acc[nt] = __builtin_amdgcn_mfma_f32_16x16x32_bf16(fa.s, fb, acc[nt], 0, 0, 0);
        }
    }

    // ---- 5) K-merge: frag buffer is dead after the barrier -> alias as red.
    __syncthreads();   // all frag ds_reads complete before overwrite
    floatx4* red = reinterpret_cast<floatx4*>(frag_lds);   // 12 KB used
    if (wk != 0) {
        #pragma unroll
        for (int nt = 0; nt < 4; ++nt)
            red[((wk - 1) * 4 + nt) * 64 + lane] = acc[nt];
    }
    __syncthreads();

    if (wk == 0) {
        const float* pb = reinterpret_cast<const float*>(bias_part);  // [h*64 + c]
        #pragma unroll
        for (int nt = 0; nt < 4; ++nt) {
            floatx4 o0 = red[(0 * 4 + nt) * 64 + lane];
            floatx4 o1 = red[(1 * 4 + nt) * 64 + lane];
            floatx4 o2 = red[(2 * 4 + nt) * 64 + lane];
            const int c = nt * 16 + n;
            float bs = 0.f;
            #pragma unroll
            for (int h = 0; h < 16; ++h)
                bs += pb[h * 64 + c];          // broadcast reads (4 lanes/addr)
            #pragma unroll
            for (int reg = 0; reg < 4; ++reg) {
                const int r = r0 + q * 4 + reg;
                out[(size_t)r * DDIM + c] =
                    (acc[nt][reg] + o0[reg] + o1[reg] + o2[reg] + bs) * (1.0f / 256.0f);
            }
        }
    }
}

extern "C" void kernel_launch(void* const* d_in, const int* in_sizes, int n_in,
                              void* d_out, int out_size, void* d_ws, size_t ws_size,
                              hipStream_t stream) {
    const float* x = (const float*)d_in[0];   // [8192, 256]
    const float* W = (const float*)d_in[1];   // [256, 64]
    const float* b = (const float*)d_in[2];   // [256, 64]
    float* out = (float*)d_out;               // [8192, 64]

    // Single dispatch: R2's two-kernel split paid a launch+gap (~4-6 us) to
    // dedup staging that is L2-hot anyway.
    nanembed_fused<<<dim3(NROWS / 16), 256, 0, stream>>>(x, W, b, out);
}

// Round 4
// 63.274 us; speedup vs baseline: 1.0224x; 1.0224x over previous
//
#include <hip/hip_runtime.h>
#include <stdint.h>

#define NROWS 8192
#define FDIM  256   // K (feature dim)
#define DDIM  64    // N (out dim)

typedef __attribute__((ext_vector_type(8))) short short8;   // 8 bf16 = 4 VGPR (MFMA A/B frag)
typedef __attribute__((ext_vector_type(4))) float floatx4;  // MFMA C/D frag

// Pack two fp32 -> bf16x2, round-to-nearest-even (inputs finite; no NaN path needed).
__device__ inline unsigned int pack2_bf16(float a, float b) {
    unsigned int ua = __float_as_uint(a);
    unsigned int ub = __float_as_uint(b);
    ua += 0x7fffu + ((ua >> 16) & 1u);
    ub += 0x7fffu + ((ub >> 16) & 1u);
    return (ua >> 16) | (ub & 0xffff0000u);
}

// ---------------------------------------------------------------------------
// Prep kernel (identical to R1/R2 — verified, at the cold-W-read latency floor):
//   blocks 0..7  : pack W[256][64] into 2048 frag-ready bf16x8 frags in ws.
//                  Frag f = ks*256 + nt*64 + lane holds
//                  W[ks*32 + (lane>>4)*8 + j][nt*16 + (lane&15)], j=0..7
//   blocks 8..11 : bias partial colsums -> ws[8192 + (blk-8)*64 + c] (4 x 64 fp32).
// ws layout (uint): [0, 8192) W frags (32 KB); [8192, 8448) bias partials.
// ---------------------------------------------------------------------------
__global__ __launch_bounds__(256)
void nanembed_prep(const float* __restrict__ W, const float* __restrict__ b,
                   unsigned int* __restrict__ ws)
{
    const int t   = threadIdx.x;
    const int blk = blockIdx.x;
    if (blk < 8) {
        const int f  = blk * 256 + t;          // 0..2047
        const int ks = f >> 8;
        const int fl = f & 63;
        const int c  = ((f >> 6) & 3) * 16 + (fl & 15);
        const float* wp = W + (size_t)(ks * 32 + (fl >> 4) * 8) * DDIM + c;
        union { short8 s; unsigned int u[4]; } fr;
        fr.u[0] = pack2_bf16(wp[0 * DDIM], wp[1 * DDIM]);
        fr.u[1] = pack2_bf16(wp[2 * DDIM], wp[3 * DDIM]);
        fr.u[2] = pack2_bf16(wp[4 * DDIM], wp[5 * DDIM]);
        fr.u[3] = pack2_bf16(wp[6 * DDIM], wp[7 * DDIM]);
        reinterpret_cast<short8*>(ws)[f] = fr.s;
    } else {
        __shared__ float part[4][64];
        const int c     = t & 63;
        const int seg   = t >> 6;
        const int fbase = (blk - 8) * 64 + seg * 16;
        float s = 0.f;
        #pragma unroll
        for (int i = 0; i < 16; ++i)
            s += b[(size_t)(fbase + i) * DDIM + c];
        part[seg][c] = s;
        __syncthreads();
        if (t < 64) {
            reinterpret_cast<float*>(ws)[8192 + (blk - 8) * 64 + t] =
                part[0][t] + part[1][t] + part[2][t] + part[3][t];
        }
    }
}

// ---------------------------------------------------------------------------
// Main kernel v4 = R2 main + all-wave epilogue + hoisted bias loads.
// Grid 512 x 256 thr (2 blocks/CU, 8 waves/CU). Block = 16 rows; wave wk
// handles k in [wk*64, +64) -> 2 ks x 4 nt = 8 MFMAs/wave. B-frags straight
// from L2-hot ws (coalesced dwordx4). K-merge: every wave writes its 4
// partial accs to LDS (16 KB); wave wk then reduces the 4 K-partials of
// column-quarter nt=wk and stores it -> all 4 waves share the epilogue
// (R2 left 3/4 of threads idle there). Bias partial loads are issued at
// kernel entry (addresses depend only on wk,n) so their latency hides
// under the x/W loads instead of being exposed after the barrier.
// Layouts (verified): A[m=lane&15][k=(lane>>4)*8+j]; D col=lane&15,
// row=(lane>>4)*4+reg.
// ---------------------------------------------------------------------------
__global__ __launch_bounds__(256, 2)
void nanembed_main(const float* __restrict__ x,
                   const unsigned int* __restrict__ ws,
                   float* __restrict__ out)
{
    __shared__ floatx4 red[4][4][64];   // 16 KB: [wave][nt][lane] partial accs

    const int tid  = threadIdx.x;    // 0..255
    const int lane = tid & 63;
    const int wk   = tid >> 6;       // K-quarter / epilogue column-quarter 0..3
    const int q    = lane >> 4;      // quad 0..3
    const int n    = lane & 15;
    const int r0   = blockIdx.x * 16;

    // ---- 0) Bias partials for this thread's epilogue column (c = wk*16+n):
    //         issue first, consumed last -> fully hidden.
    const float* pc = reinterpret_cast<const float*>(ws) + 8192;
    const int cw = wk * 16 + n;
    const float b0 = pc[cw], b1 = pc[64 + cw], b2 = pc[128 + cw], b3 = pc[192 + cw];

    // ---- 1) x loads (the only HBM-cold read): row r0+n,
    //         cols wk*64 + ks*32 + q*8 + [0,8).
    const float4* xp = reinterpret_cast<const float4*>(x)
                       + (size_t)(r0 + n) * 64 + wk * 16 + q * 2;
    float4 xv[4];
    #pragma unroll
    for (int ks = 0; ks < 2; ++ks) {
        xv[2 * ks]     = xp[ks * 8];
        xv[2 * ks + 1] = xp[ks * 8 + 1];
    }

    // ---- 2) B-frags direct from ws (L2-hot 32 KB shared by all blocks):
    //         8 coalesced dwordx4 loads, consecutive lanes -> consecutive 16B.
    const short8* wf = reinterpret_cast<const short8*>(ws);
    short8 bf[2][4];
    #pragma unroll
    for (int ks = 0; ks < 2; ++ks)
        #pragma unroll
        for (int nt = 0; nt < 4; ++nt)
            bf[ks][nt] = wf[(wk * 2 + ks) * 256 + nt * 64 + lane];

    // ---- 3) MFMA: pack A from regs, 2 ks x 4 nt = 8 MFMAs.
    floatx4 acc[4] = {{0.f, 0.f, 0.f, 0.f}, {0.f, 0.f, 0.f, 0.f},
                      {0.f, 0.f, 0.f, 0.f}, {0.f, 0.f, 0.f, 0.f}};
    #pragma unroll
    for (int ks = 0; ks < 2; ++ks) {
        union { short8 s; unsigned int u[4]; } fa;
        float4 v0 = xv[2 * ks], v1 = xv[2 * ks + 1];
        fa.u[0] = pack2_bf16(v0.x, v0.y);
        fa.u[1] = pack2_bf16(v0.z, v0.w);
        fa.u[2] = pack2_bf16(v1.x, v1.y);
        fa.u[3] = pack2_bf16(v1.z, v1.w);
        #pragma unroll
        for (int nt = 0; nt < 4; ++nt)
            acc[nt] = __builtin_amdgcn_mfma_f32_16x16x32_bf16(fa.s, bf[ks][nt], acc[nt], 0, 0, 0);
    }

    // ---- 4) K-merge, all waves: write own partials (16B/lane stride,
    //         conflict-free ds_write_b128), then wave wk reduces nt=wk.
    #pragma unroll
    for (int nt = 0; nt < 4; ++nt)
        red[wk][nt][lane] = acc[nt];
    __syncthreads();

    // ---- 5) Epilogue, all waves: 4 K-partials (static LDS indices; wk only
    //         indexes LDS, never a register array) + exact fp32 bias colsum,
    //         scale 1/256, 16 dword stores (64B-coalesced per 16-lane group).
    {
        floatx4 o0 = red[0][wk][lane];
        floatx4 o1 = red[1][wk][lane];
        floatx4 o2 = red[2][wk][lane];
        floatx4 o3 = red[3][wk][lane];
        const float bs = b0 + b1 + b2 + b3;
        #pragma unroll
        for (int reg = 0; reg < 4; ++reg) {
            const int r = r0 + q * 4 + reg;
            out[(size_t)r * DDIM + cw] =
                (o0[reg] + o1[reg] + o2[reg] + o3[reg] + bs) * (1.0f / 256.0f);
        }
    }
}

extern "C" void kernel_launch(void* const* d_in, const int* in_sizes, int n_in,
                              void* d_out, int out_size, void* d_ws, size_t ws_size,
                              hipStream_t stream) {
    const float* x = (const float*)d_in[0];   // [8192, 256]
    const float* W = (const float*)d_in[1];   // [256, 64]
    const float* b = (const float*)d_in[2];   // [256, 64]
    float* out = (float*)d_out;               // [8192, 64]
    unsigned int* ws = (unsigned int*)d_ws;   // >= 33 KB used

    // ws is re-poisoned by the harness each iteration -> prep must run in-graph.
    nanembed_prep<<<dim3(12), 256, 0, stream>>>(W, b, ws);
    nanembed_main<<<dim3(NROWS / 16), 256, 0, stream>>>(x, ws, out);
}